// Round 1
// baseline (215.080 us; speedup 1.0000x reference)
//
#include <hip/hip_runtime.h>
#include <hip/hip_bf16.h>

#define B_ 2
#define N_ 2048
#define E_ 1024
#define H_ 16
#define D_ 64
#define BH_ (B_ * H_)
#define NT_ (N_ / 64)

typedef __attribute__((ext_vector_type(4))) float f32x4;
typedef __attribute__((ext_vector_type(8))) short bf16x8;
typedef __attribute__((ext_vector_type(4))) int i32x4;
typedef __attribute__((ext_vector_type(2))) int i32x2;
typedef __attribute__((ext_vector_type(4))) _Float16 f16x4;

#define MFMA(a, b, c) __builtin_amdgcn_mfma_f32_16x16x32_bf16(a, b, c, 0, 0, 0)
#define MFMA16(a, b, c) __builtin_amdgcn_mfma_f32_16x16x16f16(a, b, c, 0, 0, 0)

#define AS1(p) ((const __attribute__((address_space(1))) unsigned int*)(p))
#define AS3(p) ((__attribute__((address_space(3))) unsigned int*)(p))

static __device__ __forceinline__ int pack2bf(float lo, float hi) {
    __hip_bfloat162 t = __float22bfloat162_rn(float2{lo, hi});
    int r;
    __builtin_memcpy(&r, &t, 4);
    return r;
}
static __device__ __forceinline__ bf16x8 cvt8s(const float* __restrict__ p, float sc) {
    f32x4 a = *(const f32x4*)p;
    f32x4 b = *(const f32x4*)(p + 4);
    i32x4 r = {pack2bf(a.x * sc, a.y * sc), pack2bf(a.z * sc, a.w * sc),
               pack2bf(b.x * sc, b.y * sc), pack2bf(b.z * sc, b.w * sc)};
    return __builtin_bit_cast(bf16x8, r);
}
// 4x f32 -> f16x4 via two v_cvt_pkrtz_f16_f32 (RTZ; P in [0,1], fine)
static __device__ __forceinline__ f16x4 pack4f16(f32x4 p) {
    auto lo = __builtin_amdgcn_cvt_pkrtz(p.x, p.y);
    auto hi = __builtin_amdgcn_cvt_pkrtz(p.z, p.w);
    f16x4 r;
    __builtin_memcpy(&r, &lo, 4);
    __builtin_memcpy(((char*)&r) + 4, &hi, 4);
    return r;
}

// ---------------------------------------------------------------------------
// Fused projections, now emitting TILED layouts consumed by attn via
// global_load_lds (linear LDS dest) + immediate-offset ds_reads:
//   Q/K (z=0/1): per 64-token tile, elem (row=tok&63, d) at
//       ((d>>3)*64 + row)*8 + (d&7)      [bf16; q pre-scaled+masked]
//   V  (z=2):    per 64-token tile, elem (d, key=tok&63) at
//       ((key>>2)*64 + d)*4 + (key&3)    [f16]
// Both layouts give conflict-free (contiguous-per-quarter-wave) frag reads.
// grid (N/64, BH, 3), block 256.
// ---------------------------------------------------------------------------
__global__ __launch_bounds__(256, 4)
void proj_kernel(const float* __restrict__ q, const float* __restrict__ k,
                 const float* __restrict__ v,
                 const float* __restrict__ Wq, const float* __restrict__ Wk,
                 const float* __restrict__ Wv,
                 const int* __restrict__ mask,
                 unsigned short* __restrict__ qh, unsigned short* __restrict__ kh,
                 unsigned short* __restrict__ vt) {
    const int z = blockIdx.z;
    const float* X = (z == 0) ? q : (z == 1) ? k : v;
    const float* W = (z == 0) ? Wq : (z == 1) ? Wk : Wv;
    unsigned short* out = (z == 0) ? qh : (z == 1) ? kh : vt;
    const float wscale = (z == 0) ? (1.44269504f * 0.03125f) : 1.0f;

    const int lane = threadIdx.x & 63;
    const int wave = threadIdx.x >> 6;
    const int l16  = lane & 15;
    const int quad = lane >> 4;
    const int bh = blockIdx.y;
    const int b = bh >> 4, h = bh & 15;
    const int n0 = blockIdx.x * 64;
    const int row = wave * 16 + l16;          // token within tile
    const int tok = n0 + row;

    const float* xrow = X + ((size_t)(b * N_ + tok)) * E_ + h * 64;
    bf16x8 xf[2];
    xf[0] = cvt8s(xrow + quad * 8, 1.0f);
    xf[1] = cvt8s(xrow + 32 + quad * 8, 1.0f);

    const float* Wh = W + (size_t)h * 64 * 64;
    bf16x8 wf[4][2];
#pragma unroll
    for (int t4 = 0; t4 < 4; ++t4) {
        const float* wrow = Wh + (t4 * 16 + l16) * 64;
        wf[t4][0] = cvt8s(wrow + quad * 8, wscale);
        wf[t4][1] = cvt8s(wrow + 32 + quad * 8, wscale);
    }

    const int mk = (z == 0) ? mask[b * N_ + tok] : 1;
    unsigned short* tbase = out + ((size_t)bh * N_ + n0) * 64;   // tile base

#pragma unroll
    for (int mi = 0; mi < 4; ++mi) {
        f32x4 a = {0.f, 0.f, 0.f, 0.f};
        a = MFMA(wf[mi][0], xf[0], a);   // D: row = dout, col = token (l16)
        a = MFMA(wf[mi][1], xf[1], a);
        if (z != 2) {
            i32x2 pk = {pack2bf(a.x, a.y), pack2bf(a.z, a.w)};
            if (!mk) pk = (i32x2){0, 0};
            // dout base = mi*16 + quad*4 -> block (mi*2 + (quad>>1)), sub (quad&1)*4
            *(i32x2*)(tbase + ((mi * 2 + (quad >> 1)) * 64 + row) * 8 +
                      (quad & 1) * 4) = pk;
        } else {
#pragma unroll
            for (int r = 0; r < 4; ++r) {
                int dout = mi * 16 + quad * 4 + r;
                _Float16 hv = (_Float16)a[r];
                unsigned short us;
                __builtin_memcpy(&us, &hv, 2);
                tbase[((row >> 2) * 64 + dout) * 4 + (row & 3)] = us;
            }
        }
    }
}

// ---------------------------------------------------------------------------
__global__ __launch_bounds__(256)
void cvt_wo_kernel(const float* __restrict__ wo, unsigned short* __restrict__ wob) {
    int idx = blockIdx.x * 256 + threadIdx.x;
    f32x4 v = *(const f32x4*)(wo + (size_t)idx * 4);
    i32x2 r = {pack2bf(v.x, v.y), pack2bf(v.z, v.w)};
    *(i32x2*)(wob + (size_t)idx * 4) = r;
}

// ---------------------------------------------------------------------------
// Flash attention v2.  Same math as before (16x16x32 QK, no-transform
// 16x16x16-f16 PV, no-max softmax, PV pipelined one tile behind QK), new
// memory choreography:
//   * K & V staged with global_load_lds (no reg round-trip, no ds_writes),
//     sources are the pre-tiled proj outputs -> fully coalesced 16B lanes.
//   * Additive block layouts: every frag ds_read is a contiguous
//     256B (b128) / 128B (b64) span per quarter-wave -> zero bank conflicts,
//     and one lane-constant address VGPR + ds immediate per array.
//   * V double-buffered (stage V(t) in iter t, consume in iter t+1);
//     whole pipeline period-2 -> unroll x2 makes all LDS addrs static.
//   * 64-q blocks (128 thr, 2 waves), grid 1024 -> 4 blocks/CU: barrier +
//     vmcnt drains of one block overlap compute of the other three.
//   * s_setprio(1) around the QK+PV MFMA cluster.
// LDS 32 KB/block.  grid (32,32): bh = 4 heads/XCD swizzle (K/V L2-resident).
// ---------------------------------------------------------------------------
__global__ __launch_bounds__(128, 2)
void attn_kernel(const unsigned short* __restrict__ qh,
                 const unsigned short* __restrict__ kh,
                 const unsigned short* __restrict__ vt,
                 unsigned short* __restrict__ attnb) {
    __shared__ short Kb[2][4096];   // 8 KB each
    __shared__ short Vb[2][4096];

    const int tid  = threadIdx.x;       // 0..127
    const int lane = tid & 63;
    const int wave = tid >> 6;          // 0..1
    const int l16  = lane & 15;
    const int quad = lane >> 4;

    const int flat = blockIdx.y * gridDim.x + blockIdx.x;    // 0..1023
    const int qblk = flat >> 5;                              // 0..31
    const int rem  = flat & 31;
    const int bh   = ((rem & 7) << 2) | (rem >> 3);          // 4 heads per XCD
    const int b = bh >> 4, h = bh & 15;
    const int q0 = qblk * 64 + wave * 32;

    const unsigned short* kbase = kh + (size_t)bh * N_ * 64;
    const unsigned short* vbase = vt + (size_t)bh * N_ * 64;
    const unsigned short* qtile = qh + ((size_t)bh * N_ + qblk * 64) * 64;

    // Q frags from tiled layout: (q=row, d=(half*4+quad)*8..+7)
    bf16x8 qf[2][2];
#pragma unroll
    for (int qi = 0; qi < 2; ++qi)
#pragma unroll
        for (int half = 0; half < 2; ++half)
            qf[qi][half] = *(const bf16x8*)(qtile +
                ((half * 4 + quad) * 64 + wave * 32 + qi * 16 + l16) * 8);

    f32x4 psum[2] = {{0.f, 0.f, 0.f, 0.f}, {0.f, 0.f, 0.f, 0.f}};
    f32x4 o[4][2];
#pragma unroll
    for (int mi = 0; mi < 4; ++mi)
#pragma unroll
        for (int qi = 0; qi < 2; ++qi) o[mi][qi] = (f32x4){0.f, 0.f, 0.f, 0.f};

    f16x4 pf[2][4];   // saved P frags (16x16x16 B-operand) from previous tile

    // prologue: DMA K tile 0 into Kb[0]
#pragma unroll
    for (int i = 0; i < 4; ++i)
        __builtin_amdgcn_global_load_lds(AS1(kbase + tid * 8 + i * 1024),
                                         AS3(&Kb[0][tid * 8 + i * 1024]), 16, 0, 0);
    __syncthreads();

// BODY(T, CUR, DO_PV, DO_STAGEK): one k-tile.  CUR = T&1 (literal).
// K(T+1) DMA -> Kb[CUR^1]; V(T) DMA -> Vb[CUR] (consumed next iter);
// PV(T-1) reads Vb[CUR^1].  One barrier (implicit vmcnt/lgkm drain).
#define BODY(T, CUR, DO_PV, DO_STAGEK)                                           \
    {                                                                            \
        if (DO_STAGEK) {                                                         \
            const unsigned short* ksrc = kbase + (size_t)((T) + 1) * 4096;       \
            _Pragma("unroll")                                                    \
            for (int i = 0; i < 4; ++i)                                          \
                __builtin_amdgcn_global_load_lds(                                \
                    AS1(ksrc + tid * 8 + i * 1024),                              \
                    AS3(&Kb[(CUR) ^ 1][tid * 8 + i * 1024]), 16, 0, 0);          \
        }                                                                        \
        {                                                                        \
            const unsigned short* vsrc = vbase + (size_t)(T) * 4096;             \
            _Pragma("unroll")                                                    \
            for (int i = 0; i < 4; ++i)                                          \
                __builtin_amdgcn_global_load_lds(                                \
                    AS1(vsrc + tid * 8 + i * 1024),                              \
                    AS3(&Vb[CUR][tid * 8 + i * 1024]), 16, 0, 0);                \
        }                                                                        \
        __builtin_amdgcn_s_setprio(1);                                           \
        f32x4 s[2][4];                                                           \
        _Pragma("unroll")                                                        \
        for (int t4 = 0; t4 < 4; ++t4) {                                         \
            bf16x8 ka0 = *(const bf16x8*)(&Kb[CUR][((0 * 4 + quad) * 64 +        \
                                                    t4 * 16 + l16) * 8]);        \
            bf16x8 ka1 = *(const bf16x8*)(&Kb[CUR][((1 * 4 + quad) * 64 +        \
                                                    t4 * 16 + l16) * 8]);        \
            _Pragma("unroll")                                                    \
            for (int qi = 0; qi < 2; ++qi) {                                     \
                f32x4 zz = {0.f, 0.f, 0.f, 0.f};                                 \
                zz = MFMA(ka0, qf[qi][0], zz);                                   \
                zz = MFMA(ka1, qf[qi][1], zz);                                   \
                s[qi][t4] = zz;                                                  \
            }                                                                    \
        }                                                                        \
        if (DO_PV) {                                                             \
            _Pragma("unroll")                                                    \
            for (int mi = 0; mi < 4; ++mi) {                                     \
                _Pragma("unroll")                                                \
                for (int t4 = 0; t4 < 4; ++t4) {                                 \
                    f16x4 va = *(const f16x4*)(&Vb[(CUR) ^ 1][                   \
                        ((t4 * 4 + quad) * 64 + mi * 16 + l16) * 4]);            \
                    _Pragma("unroll")                                            \
                    for (int qi = 0; qi < 2; ++qi)                               \
                        o[mi][qi] = MFMA16(va, pf[qi][t4], o[mi][qi]);           \
                }                                                                \
            }                                                                    \
        }                                                                        \
        __builtin_amdgcn_s_setprio(0);                                           \
        _Pragma("unroll")                                                        \
        for (int qi = 0; qi < 2; ++qi) {                                         \
            _Pragma("unroll")                                                    \
            for (int t4 = 0; t4 < 4; ++t4) {                                     \
                f32x4 p;                                                         \
                _Pragma("unroll")                                                \
                for (int r = 0; r < 4; ++r)                                      \
                    p[r] = __builtin_amdgcn_exp2f(s[qi][t4][r]);                 \
                psum[qi] += p;                                                   \
                pf[qi][t4] = pack4f16(p);                                        \
            }                                                                    \
        }                                                                        \
        __syncthreads();                                                         \
    }

    BODY(0, 0, 0, 1)
    for (int t = 1; t < NT_ - 1; t += 2) {   // rolled loop: bodies 1..30
        BODY(t, 1, 1, 1)
        BODY(t + 1, 0, 1, 1)
    }
    BODY(NT_ - 1, 1, 1, 0)

    // drain: PV for the last tile (V(31) sits in Vb[1], drained by barrier)
#pragma unroll
    for (int mi = 0; mi < 4; ++mi) {
#pragma unroll
        for (int t4 = 0; t4 < 4; ++t4) {
            f16x4 va = *(const f16x4*)(&Vb[1][((t4 * 4 + quad) * 64 +
                                               mi * 16 + l16) * 4]);
#pragma unroll
            for (int qi = 0; qi < 2; ++qi)
                o[mi][qi] = MFMA16(va, pf[qi][t4], o[mi][qi]);
        }
    }
#undef BODY

    // row-sum reduction (once per kernel)
#pragma unroll
    for (int qi = 0; qi < 2; ++qi) {
        float rs = psum[qi].x + psum[qi].y + psum[qi].z + psum[qi].w;
        rs += __shfl_xor(rs, 16);
        rs += __shfl_xor(rs, 32);
        const float inv = 1.0f / rs;
        const int qrow_idx = q0 + qi * 16 + l16;
#pragma unroll
        for (int mi = 0; mi < 4; ++mi) {
            f32x4 ov = o[mi][qi];
            i32x2 pkk = {pack2bf(ov.x * inv, ov.y * inv),
                         pack2bf(ov.z * inv, ov.w * inv)};
            int d0 = mi * 16 + quad * 4;
            *(i32x2*)(attnb + ((size_t)(b * N_ + qrow_idx)) * E_ + h * 64 + d0) = pkk;
        }
    }
}

// ---------------------------------------------------------------------------
// out = attnb(4096x1024 bf16) @ wob^T(1024x1024) -> fp32.  128x128 tile,
// BK=32, global_load_lds w16, dbuf LDS (chunk-linear), 512 thr = 8 waves
// (2m x 4n of 64x32), 1 chunk/thread/array per stage.  grid (32,8).
// ---------------------------------------------------------------------------
__global__ __launch_bounds__(512, 1)
void out_gemm_kernel(const unsigned short* __restrict__ A,
                     const unsigned short* __restrict__ Bw,
                     float* __restrict__ out) {
    __shared__ short As[2][128 * 32];   // 8 KB each
    __shared__ short Bs[2][128 * 32];

    const int tid  = threadIdx.x;
    const int lane = tid & 63;
    const int l16  = lane & 15;
    const int quad = lane >> 4;
    const int wave = tid >> 6;
    const int wm = wave & 1, wn = wave >> 1;
    const int m0 = blockIdx.x * 128;
    const int n0 = blockIdx.y * 128;

    const unsigned short* gA = A + (size_t)m0 * E_;
    const unsigned short* gB = Bw + (size_t)n0 * E_;

    f32x4 acc[4][2];
#pragma unroll
    for (int mt = 0; mt < 4; ++mt)
#pragma unroll
        for (int nt = 0; nt < 2; ++nt) acc[mt][nt] = (f32x4){0.f, 0.f, 0.f, 0.f};

    const int cc = tid >> 7, rr = tid & 127;
#define OG_STAGE(buf, k0)                                                        \
    {                                                                            \
        __builtin_amdgcn_global_load_lds(AS1(gA + (size_t)rr * E_ + (k0) + cc * 8), \
                                         AS3(&As[buf][tid * 8]), 16, 0, 0);      \
        __builtin_amdgcn_global_load_lds(AS1(gB + (size_t)rr * E_ + (k0) + cc * 8), \
                                         AS3(&Bs[buf][tid * 8]), 16, 0, 0);      \
    }

    OG_STAGE(0, 0)
    __syncthreads();

    for (int kt = 0; kt < E_ / 32; ++kt) {
        const int cur = kt & 1;
        if (kt + 1 < E_ / 32) OG_STAGE(cur ^ 1, (kt + 1) * 32)

        bf16x8 af[4], bf[2];
#pragma unroll
        for (int mt = 0; mt < 4; ++mt)
            af[mt] = *(const bf16x8*)(&As[cur][(quad * 128 + wm * 64 + mt * 16 + l16) * 8]);
#pragma unroll
        for (int nt = 0; nt < 2; ++nt)
            bf[nt] = *(const bf16x8*)(&Bs[cur][(quad * 128 + wn * 32 + nt * 16 + l16) * 8]);

#pragma unroll
        for (int mt = 0; mt < 4; ++mt)
#pragma unroll
            for (int nt = 0; nt < 2; ++nt)
                acc[mt][nt] = MFMA(af[mt], bf[nt], acc[mt][nt]);

        __syncthreads();
    }

#pragma unroll
    for (int mt = 0; mt < 4; ++mt)
#pragma unroll
        for (int nt = 0; nt < 2; ++nt)
#pragma unroll
            for (int r = 0; r < 4; ++r)
                out[(size_t)(m0 + wm * 64 + mt * 16 + quad * 4 + r) * E_ +
                    n0 + wn * 32 + nt * 16 + l16] = acc[mt][nt][r];
#undef OG_STAGE
}

// ---------------------------------------------------------------------------
extern "C" void kernel_launch(void* const* d_in, const int* in_sizes, int n_in,
                              void* d_out, int out_size, void* d_ws, size_t ws_size,
                              hipStream_t stream) {
    const float* q    = (const float*)d_in[0];
    const float* k    = (const float*)d_in[1];
    const float* v    = (const float*)d_in[2];
    const int*   mask = (const int*)d_in[3];
    const float* Wq   = (const float*)d_in[4];
    const float* Wk   = (const float*)d_in[5];
    const float* Wv   = (const float*)d_in[6];
    const float* Wo   = (const float*)d_in[7];
    float* out = (float*)d_out;

    char* ws = (char*)d_ws;
    unsigned short* qh    = (unsigned short*)(ws);
    unsigned short* kh    = (unsigned short*)(ws + (size_t)8 * 1024 * 1024);
    unsigned short* vt    = (unsigned short*)(ws + (size_t)16 * 1024 * 1024);
    unsigned short* attnb = (unsigned short*)(ws + (size_t)24 * 1024 * 1024);
    // wob aliases qh's region: cvt_wo runs AFTER attn is done reading qh.
    unsigned short* wob   = (unsigned short*)(ws);

    proj_kernel<<<dim3(N_ / 64, BH_, 3), dim3(256), 0, stream>>>(q, k, v, Wq, Wk, Wv,
                                                                 mask, qh, kh, vt);
    attn_kernel<<<dim3(32, 32), dim3(128), 0, stream>>>(qh, kh, vt, attnb);
    cvt_wo_kernel<<<dim3(E_ * E_ / 1024), dim3(256), 0, stream>>>(Wo, wob);
    out_gemm_kernel<<<dim3(32, 8), dim3(512), 0, stream>>>(attnb, wob, out);
}

// Round 2
// 202.997 us; speedup vs baseline: 1.0595x; 1.0595x over previous
//
#include <hip/hip_runtime.h>
#include <hip/hip_bf16.h>

#define B_ 2
#define N_ 2048
#define E_ 1024
#define H_ 16
#define D_ 64
#define BH_ (B_ * H_)

typedef __attribute__((ext_vector_type(4))) float f32x4;
typedef __attribute__((ext_vector_type(8))) short bf16x8;
typedef __attribute__((ext_vector_type(4))) short s16x4;
typedef __attribute__((ext_vector_type(4))) int i32x4;
typedef __attribute__((ext_vector_type(2))) int i32x2;
typedef __attribute__((ext_vector_type(4))) _Float16 f16x4;

#define MFMA(a, b, c) __builtin_amdgcn_mfma_f32_16x16x32_bf16(a, b, c, 0, 0, 0)
#define MFMA16(a, b, c) __builtin_amdgcn_mfma_f32_16x16x16f16(a, b, c, 0, 0, 0)

#define AS1(p) ((const __attribute__((address_space(1))) unsigned int*)(p))
#define AS3(p) ((__attribute__((address_space(3))) unsigned int*)(p))

static __device__ __forceinline__ int pack2bf(float lo, float hi) {
    __hip_bfloat162 t = __float22bfloat162_rn(float2{lo, hi});
    int r;
    __builtin_memcpy(&r, &t, 4);
    return r;
}
static __device__ __forceinline__ bf16x8 cvt8s(const float* __restrict__ p, float sc) {
    f32x4 a = *(const f32x4*)p;
    f32x4 b = *(const f32x4*)(p + 4);
    i32x4 r = {pack2bf(a.x * sc, a.y * sc), pack2bf(a.z * sc, a.w * sc),
               pack2bf(b.x * sc, b.y * sc), pack2bf(b.z * sc, b.w * sc)};
    return __builtin_bit_cast(bf16x8, r);
}
// 4x f32 -> f16x4 via two v_cvt_pkrtz_f16_f32 (RTZ; P in [0,1], fine)
static __device__ __forceinline__ f16x4 pack4f16(f32x4 p) {
    auto lo = __builtin_amdgcn_cvt_pkrtz(p.x, p.y);   // __fp16 x2
    auto hi = __builtin_amdgcn_cvt_pkrtz(p.z, p.w);
    f16x4 r;
    __builtin_memcpy(&r, &lo, 4);
    __builtin_memcpy(((char*)&r) + 4, &hi, 4);
    return r;
}

// ---------------------------------------------------------------------------
// Fused projections: z=0 -> qh = (q@Wq^T)*log2e/32, masked rows zeroed,
// layout [bh][n][d] bf16; z=1 -> kh [bh][n][d] bf16;
// z=2 -> vt [bh][d][n] in F16 (PV runs f16 16x16x16 MFMA).
// grid (N/64, BH, 3), block 256.   [round-0 proven structure]
// ---------------------------------------------------------------------------
__global__ __launch_bounds__(256, 4)
void proj_kernel(const float* __restrict__ q, const float* __restrict__ k,
                 const float* __restrict__ v,
                 const float* __restrict__ Wq, const float* __restrict__ Wk,
                 const float* __restrict__ Wv,
                 const int* __restrict__ mask,
                 unsigned short* __restrict__ qh, unsigned short* __restrict__ kh,
                 unsigned short* __restrict__ vt) {
    const int z = blockIdx.z;
    const float* X = (z == 0) ? q : (z == 1) ? k : v;
    const float* W = (z == 0) ? Wq : (z == 1) ? Wk : Wv;
    unsigned short* out = (z == 0) ? qh : (z == 1) ? kh : vt;
    const float wscale = (z == 0) ? (1.44269504f * 0.03125f) : 1.0f;

    const int lane = threadIdx.x & 63;
    const int wave = threadIdx.x >> 6;
    const int l16  = lane & 15;
    const int quad = lane >> 4;
    const int bh = blockIdx.y;
    const int b = bh >> 4, h = bh & 15;
    const int n0 = blockIdx.x * 64;
    const int tok = n0 + wave * 16 + l16;

    const float* xrow = X + ((size_t)(b * N_ + tok)) * E_ + h * 64;
    bf16x8 xf[2];
    xf[0] = cvt8s(xrow + quad * 8, 1.0f);
    xf[1] = cvt8s(xrow + 32 + quad * 8, 1.0f);

    const float* Wh = W + (size_t)h * 64 * 64;
    bf16x8 wf[4][2];
#pragma unroll
    for (int t4 = 0; t4 < 4; ++t4) {
        const float* wrow = Wh + (t4 * 16 + l16) * 64;
        wf[t4][0] = cvt8s(wrow + quad * 8, wscale);
        wf[t4][1] = cvt8s(wrow + 32 + quad * 8, wscale);
    }

    const int mk = (z == 0) ? mask[b * N_ + tok] : 1;

#pragma unroll
    for (int mi = 0; mi < 4; ++mi) {
        f32x4 a = {0.f, 0.f, 0.f, 0.f};
        a = MFMA(wf[mi][0], xf[0], a);   // D: row = dout, col = token (l16)
        a = MFMA(wf[mi][1], xf[1], a);
        if (z != 2) {
            i32x2 pk = {pack2bf(a.x, a.y), pack2bf(a.z, a.w)};
            if (!mk) pk = (i32x2){0, 0};
            *(i32x2*)(out + ((size_t)bh * N_ + tok) * 64 + mi * 16 + quad * 4) = pk;
        } else {
#pragma unroll
            for (int r = 0; r < 4; ++r) {
                int dout = mi * 16 + quad * 4 + r;
                _Float16 hv = (_Float16)a[r];
                unsigned short us;
                __builtin_memcpy(&us, &hv, 2);
                out[((size_t)bh * 64 + dout) * N_ + tok] = us;
            }
        }
    }
}

// ---------------------------------------------------------------------------
__global__ __launch_bounds__(256)
void cvt_wo_kernel(const float* __restrict__ wo, unsigned short* __restrict__ wob) {
    int idx = blockIdx.x * 256 + threadIdx.x;
    f32x4 v = *(const f32x4*)(wo + (size_t)idx * 4);
    i32x2 r = {pack2bf(v.x, v.y), pack2bf(v.z, v.w)};
    *(i32x2*)(wob + (size_t)idx * 4) = r;
}

// ---------------------------------------------------------------------------
// Flash attention (round-0 proven structure + s_setprio around MFMA).
// PV uses v_mfma_f32_16x16x16_f16 whose B-operand layout EQUALS the QK C/D
// layout -> P needs NO cross-lane transform.  V stored/staged as f16.
// K dbuf [64][72]; V triple-buffer [64][76] (2-way residue conflicts only).
// PV(t-1) pipelined behind QK(t).  No-max softmax; qh pre-scaled+masked.
// One barrier/iter.  grid (16,32)=512 (XCD swizzle: 4 heads/XCD).
// setprio(1) spans QK+PV MFMA clusters so MFMA-phase waves win issue
// arbitration over exp2-phase waves (T5, m191).
// ---------------------------------------------------------------------------
__global__ __launch_bounds__(256, 2)
void attn_kernel(const unsigned short* __restrict__ qh,
                 const unsigned short* __restrict__ kh,
                 const unsigned short* __restrict__ vt,
                 unsigned short* __restrict__ attnb) {
    __shared__ short Kb[2][64 * 72];   // 18 KB
    __shared__ short Vb[3][64 * 76];   // 28.5 KB

    const int tid  = threadIdx.x;
    const int lane = tid & 63;
    const int wave = tid >> 6;
    const int l16  = lane & 15;
    const int quad = lane >> 4;

    const int flat = blockIdx.y * gridDim.x + blockIdx.x;   // 0..511
    const int qblk = flat >> 5;
    const int rem  = flat & 31;
    const int bh   = ((rem & 7) << 2) | (rem >> 3);          // 4 heads per XCD
    const int b = bh >> 4, h = bh & 15;
    const int q0 = qblk * 128 + wave * 32;

    const unsigned short* kbase = kh + (size_t)bh * N_ * 64;
    const unsigned short* vbase = vt + (size_t)bh * 64 * N_;

    const int c0i = tid;
    const int c1i = tid + 256;
    const int k0o = (c0i >> 3) * 72 + (c0i & 7) * 8;
    const int k1o = (c1i >> 3) * 72 + (c1i & 7) * 8;
    const int v0o = (c0i >> 3) * 76 + (c0i & 7) * 8;
    const int v1o = (c1i >> 3) * 76 + (c1i & 7) * 8;

    short* kcur  = &Kb[0][0];
    short* knext = &Kb[1][0];
    short* vprev = &Vb[2][0];
    short* vcur  = &Vb[0][0];
    short* vnext = &Vb[1][0];

    bf16x8 qf[2][2];
#pragma unroll
    for (int qi = 0; qi < 2; ++qi) {
        const unsigned short* qrow = qh + ((size_t)bh * N_ + q0 + qi * 16 + l16) * 64;
        qf[qi][0] = *(const bf16x8*)(qrow + quad * 8);
        qf[qi][1] = *(const bf16x8*)(qrow + 32 + quad * 8);
    }

    f32x4 psum[2] = {{0.f, 0.f, 0.f, 0.f}, {0.f, 0.f, 0.f, 0.f}};
    f32x4 o[4][2];
#pragma unroll
    for (int mi = 0; mi < 4; ++mi)
#pragma unroll
        for (int qi = 0; qi < 2; ++qi) o[mi][qi] = (f32x4){0.f, 0.f, 0.f, 0.f};

    f16x4 pf[2][4];   // saved P frags (16x16x16 B-operand) from previous tile

    // stage tile 0
    bf16x8 gK0, gK1, gV0, gV1;
    gK0 = *(const bf16x8*)(kbase + c0i * 8);
    gK1 = *(const bf16x8*)(kbase + c1i * 8);
    gV0 = *(const bf16x8*)(vbase + (size_t)(c0i >> 3) * N_ + (c0i & 7) * 8);
    gV1 = *(const bf16x8*)(vbase + (size_t)(c1i >> 3) * N_ + (c1i & 7) * 8);
    *(bf16x8*)(kcur + k0o) = gK0;
    *(bf16x8*)(kcur + k1o) = gK1;
    *(bf16x8*)(vcur + v0o) = gV0;
    *(bf16x8*)(vcur + v1o) = gV1;
    __syncthreads();

    for (int kt = 0; kt < N_ / 64; ++kt) {
        // global prefetch of tile kt+1
        if (kt + 1 < N_ / 64) {
            const int k0n = (kt + 1) * 64;
            gK0 = *(const bf16x8*)(kbase + (size_t)k0n * 64 + c0i * 8);
            gK1 = *(const bf16x8*)(kbase + (size_t)k0n * 64 + c1i * 8);
            gV0 = *(const bf16x8*)(vbase + (size_t)(c0i >> 3) * N_ + k0n + (c0i & 7) * 8);
            gV1 = *(const bf16x8*)(vbase + (size_t)(c1i >> 3) * N_ + k0n + (c1i & 7) * 8);
        }

        // K frags + QK^T for tile kt  (high prio: MFMA cluster)
        __builtin_amdgcn_s_setprio(1);
        bf16x8 ka[4][2];
#pragma unroll
        for (int t4 = 0; t4 < 4; ++t4) {
            ka[t4][0] = *(const bf16x8*)(kcur + (t4 * 16 + l16) * 72 + quad * 8);
            ka[t4][1] = *(const bf16x8*)(kcur + (t4 * 16 + l16) * 72 + 32 + quad * 8);
        }
        f32x4 s[2][4];
#pragma unroll
        for (int qi = 0; qi < 2; ++qi)
#pragma unroll
            for (int t4 = 0; t4 < 4; ++t4) {
                f32x4 z = {0.f, 0.f, 0.f, 0.f};
                z = MFMA(ka[t4][0], qf[qi][0], z);
                z = MFMA(ka[t4][1], qf[qi][1], z);
                s[qi][t4] = z;
            }

        // PV for tile kt-1 (independent of this iter's chain)
        if (kt > 0) {
#pragma unroll
            for (int mi = 0; mi < 4; ++mi) {
#pragma unroll
                for (int t4 = 0; t4 < 4; ++t4) {
                    f16x4 va = *(const f16x4*)(vprev + (mi * 16 + l16) * 76 +
                                               t4 * 16 + quad * 4);
#pragma unroll
                    for (int qi = 0; qi < 2; ++qi)
                        o[mi][qi] = MFMA16(va, pf[qi][t4], o[mi][qi]);
                }
            }
        }
        __builtin_amdgcn_s_setprio(0);

        // softmax tile kt -> pf (NO transform: C-layout == 16x16x16 B-layout)
#pragma unroll
        for (int qi = 0; qi < 2; ++qi) {
#pragma unroll
            for (int t4 = 0; t4 < 4; ++t4) {
                f32x4 p;
#pragma unroll
                for (int r = 0; r < 4; ++r) p[r] = __builtin_amdgcn_exp2f(s[qi][t4][r]);
                psum[qi] += p;
                pf[qi][t4] = pack4f16(p);
            }
        }

        // stage tile kt+1, one barrier
        if (kt + 1 < N_ / 64) {
            *(bf16x8*)(knext + k0o) = gK0;
            *(bf16x8*)(knext + k1o) = gK1;
            *(bf16x8*)(vnext + v0o) = gV0;
            *(bf16x8*)(vnext + v1o) = gV1;
            __syncthreads();
        }

        // rotate buffers
        short* t = kcur; kcur = knext; knext = t;
        short* tv = vprev; vprev = vcur; vcur = vnext; vnext = tv;
    }

    // drain: PV for the last tile
    __builtin_amdgcn_s_setprio(1);
#pragma unroll
    for (int mi = 0; mi < 4; ++mi) {
#pragma unroll
        for (int t4 = 0; t4 < 4; ++t4) {
            f16x4 va = *(const f16x4*)(vprev + (mi * 16 + l16) * 76 +
                                       t4 * 16 + quad * 4);
#pragma unroll
            for (int qi = 0; qi < 2; ++qi)
                o[mi][qi] = MFMA16(va, pf[qi][t4], o[mi][qi]);
        }
    }
    __builtin_amdgcn_s_setprio(0);

    // row-sum reduction (once per kernel, not per iter)
#pragma unroll
    for (int qi = 0; qi < 2; ++qi) {
        float rs = psum[qi].x + psum[qi].y + psum[qi].z + psum[qi].w;
        rs += __shfl_xor(rs, 16);
        rs += __shfl_xor(rs, 32);
        const float inv = 1.0f / rs;
        const int qrow_idx = q0 + qi * 16 + l16;
#pragma unroll
        for (int mi = 0; mi < 4; ++mi) {
            f32x4 ov = o[mi][qi];
            i32x2 pkk = {pack2bf(ov.x * inv, ov.y * inv),
                         pack2bf(ov.z * inv, ov.w * inv)};
            int d0 = mi * 16 + quad * 4;
            *(i32x2*)(attnb + ((size_t)(b * N_ + qrow_idx)) * E_ + h * 64 + d0) = pkk;
        }
    }
}

// ---------------------------------------------------------------------------
// out = attnb(4096x1024 bf16) @ wob^T(1024x1024) -> fp32.
// v2: BM=64, BN=128, BK=64 -> grid (64,8) = 512 blocks = 2 blocks/CU
// (was 1), 16 K-iters (was 32) -> half the barrier drains, two barrier
// groups per CU to overlap them.  Chunk-linear LDS ([colblock][row][8],
// 2-way-free b128 frag reads), global_load_lds w16, dbuf.  512 thr = 8
// waves (2m x 4n of 32x32).
// ---------------------------------------------------------------------------
__global__ __launch_bounds__(512, 4)
void out_gemm_kernel(const unsigned short* __restrict__ A,
                     const unsigned short* __restrict__ Bw,
                     float* __restrict__ out) {
    __shared__ short As[2][64 * 64];    // 8 KB per buf
    __shared__ short Bs[2][128 * 64];   // 16 KB per buf

    const int tid  = threadIdx.x;       // 0..511
    const int lane = tid & 63;
    const int l16  = lane & 15;
    const int quad = lane >> 4;
    const int wave = tid >> 6;          // 0..7
    const int wm = wave >> 2;           // 0..1 -> 32-row subtile
    const int wn = wave & 3;            // 0..3 -> 32-col subtile
    const int m0 = blockIdx.x * 64;
    const int n0 = blockIdx.y * 128;

    const unsigned short* gA = A + (size_t)m0 * E_;
    const unsigned short* gB = Bw + (size_t)n0 * E_;

    f32x4 acc[2][2];
#pragma unroll
    for (int mt = 0; mt < 2; ++mt)
#pragma unroll
        for (int nt = 0; nt < 2; ++nt) acc[mt][nt] = (f32x4){0.f, 0.f, 0.f, 0.f};

    // A tile: 64 rows x 64 cols = 512 16B-chunks; chunk c: cb=c>>6, row=c&63.
    // B tile: 128 rows x 64 cols = 1024 chunks; chunk c: cb=c>>7, row=c&127.
    // LDS layout = chunk-linear: chunk c at [c*8] shorts -> [cb][row][8].
#define OG_STAGE(buf, k0)                                                          \
    {                                                                              \
        __builtin_amdgcn_global_load_lds(                                          \
            AS1(gA + (size_t)(tid & 63) * E_ + (k0) + (tid >> 6) * 8),             \
            AS3(&As[buf][tid * 8]), 16, 0, 0);                                     \
        __builtin_amdgcn_global_load_lds(                                          \
            AS1(gB + (size_t)(tid & 127) * E_ + (k0) + (tid >> 7) * 8),            \
            AS3(&Bs[buf][tid * 8]), 16, 0, 0);                                     \
        __builtin_amdgcn_global_load_lds(                                          \
            AS1(gB + (size_t)(tid & 127) * E_ + (k0) + ((tid + 512) >> 7) * 8),    \
            AS3(&Bs[buf][(tid + 512) * 8]), 16, 0, 0);                             \
    }

    OG_STAGE(0, 0)
    __syncthreads();

    for (int kt = 0; kt < E_ / 64; ++kt) {
        const int cur = kt & 1;
        if (kt + 1 < E_ / 64) OG_STAGE(cur ^ 1, (kt + 1) * 64)

        __builtin_amdgcn_s_setprio(1);
#pragma unroll
        for (int kh = 0; kh < 2; ++kh) {
            bf16x8 af[2], bf[2];
#pragma unroll
            for (int mt = 0; mt < 2; ++mt)
                af[mt] = *(const bf16x8*)(&As[cur][((kh * 4 + quad) * 64 +
                                                    wm * 32 + mt * 16 + l16) * 8]);
#pragma unroll
            for (int nt = 0; nt < 2; ++nt)
                bf[nt] = *(const bf16x8*)(&Bs[cur][((kh * 4 + quad) * 128 +
                                                    wn * 32 + nt * 16 + l16) * 8]);
#pragma unroll
            for (int mt = 0; mt < 2; ++mt)
#pragma unroll
                for (int nt = 0; nt < 2; ++nt)
                    acc[mt][nt] = MFMA(af[mt], bf[nt], acc[mt][nt]);
        }
        __builtin_amdgcn_s_setprio(0);

        __syncthreads();
    }

#pragma unroll
    for (int mt = 0; mt < 2; ++mt)
#pragma unroll
        for (int nt = 0; nt < 2; ++nt)
#pragma unroll
            for (int r = 0; r < 4; ++r)
                out[(size_t)(m0 + wm * 32 + mt * 16 + quad * 4 + r) * E_ +
                    n0 + wn * 32 + nt * 16 + l16] = acc[mt][nt][r];
#undef OG_STAGE
}

// ---------------------------------------------------------------------------
extern "C" void kernel_launch(void* const* d_in, const int* in_sizes, int n_in,
                              void* d_out, int out_size, void* d_ws, size_t ws_size,
                              hipStream_t stream) {
    const float* q    = (const float*)d_in[0];
    const float* k    = (const float*)d_in[1];
    const float* v    = (const float*)d_in[2];
    const int*   mask = (const int*)d_in[3];
    const float* Wq   = (const float*)d_in[4];
    const float* Wk   = (const float*)d_in[5];
    const float* Wv   = (const float*)d_in[6];
    const float* Wo   = (const float*)d_in[7];
    float* out = (float*)d_out;

    char* ws = (char*)d_ws;
    unsigned short* qh    = (unsigned short*)(ws);
    unsigned short* kh    = (unsigned short*)(ws + (size_t)8 * 1024 * 1024);
    unsigned short* vt    = (unsigned short*)(ws + (size_t)16 * 1024 * 1024);
    unsigned short* attnb = (unsigned short*)(ws + (size_t)24 * 1024 * 1024);
    // wob aliases qh's region: cvt_wo runs AFTER attn is done reading qh.
    unsigned short* wob   = (unsigned short*)(ws);

    dim3 blk(256);
    proj_kernel<<<dim3(N_ / 64, BH_, 3), blk, 0, stream>>>(q, k, v, Wq, Wk, Wv, mask,
                                                           qh, kh, vt);
    attn_kernel<<<dim3(16, 32), blk, 0, stream>>>(qh, kh, vt, attnb);
    cvt_wo_kernel<<<dim3(E_ * E_ / 1024), blk, 0, stream>>>(Wo, wob);
    out_gemm_kernel<<<dim3(64, 8), dim3(512), 0, stream>>>(attnb, wob, out);
}

// Round 3
// 197.468 us; speedup vs baseline: 1.0892x; 1.0280x over previous
//
#include <hip/hip_runtime.h>
#include <hip/hip_bf16.h>

#define B_ 2
#define N_ 2048
#define E_ 1024
#define H_ 16
#define D_ 64
#define BH_ (B_ * H_)

typedef __attribute__((ext_vector_type(4))) float f32x4;
typedef __attribute__((ext_vector_type(8))) short bf16x8;
typedef __attribute__((ext_vector_type(4))) short s16x4;
typedef __attribute__((ext_vector_type(4))) int i32x4;
typedef __attribute__((ext_vector_type(2))) int i32x2;
typedef __attribute__((ext_vector_type(4))) _Float16 f16x4;

#define MFMA(a, b, c) __builtin_amdgcn_mfma_f32_16x16x32_bf16(a, b, c, 0, 0, 0)
#define MFMA16(a, b, c) __builtin_amdgcn_mfma_f32_16x16x16f16(a, b, c, 0, 0, 0)

#define AS1(p) ((const __attribute__((address_space(1))) unsigned int*)(p))
#define AS3(p) ((__attribute__((address_space(3))) unsigned int*)(p))

static __device__ __forceinline__ int pack2bf(float lo, float hi) {
    __hip_bfloat162 t = __float22bfloat162_rn(float2{lo, hi});
    int r;
    __builtin_memcpy(&r, &t, 4);
    return r;
}
static __device__ __forceinline__ bf16x8 cvt8s(const float* __restrict__ p, float sc) {
    f32x4 a = *(const f32x4*)p;
    f32x4 b = *(const f32x4*)(p + 4);
    i32x4 r = {pack2bf(a.x * sc, a.y * sc), pack2bf(a.z * sc, a.w * sc),
               pack2bf(b.x * sc, b.y * sc), pack2bf(b.z * sc, b.w * sc)};
    return __builtin_bit_cast(bf16x8, r);
}
// 4x f32 -> f16x4 via two v_cvt_pkrtz_f16_f32 (RTZ; P in [0,1], fine)
static __device__ __forceinline__ f16x4 pack4f16(f32x4 p) {
    auto lo = __builtin_amdgcn_cvt_pkrtz(p.x, p.y);   // __fp16 x2
    auto hi = __builtin_amdgcn_cvt_pkrtz(p.z, p.w);
    f16x4 r;
    __builtin_memcpy(&r, &lo, 4);
    __builtin_memcpy(((char*)&r) + 4, &hi, 4);
    return r;
}

// ---------------------------------------------------------------------------
// Fused projections: z=0 -> qh = (q@Wq^T)*log2e/32, masked rows zeroed,
// layout [bh][n][d] bf16; z=1 -> kh [bh][n][d] bf16;
// z=2 -> vt [bh][d][n] in F16 (PV runs f16 16x16x16 MFMA);
// z=3 (when launched with gridDim.z==4) -> Wo fp32 -> bf16 convert
// (folds the old cvt_wo launch into this grid; wob must NOT alias qh).
// grid (N/64, BH, 3|4), block 256.  bounds (256,2): the hoisted W+X
// staging peaks >128 VGPR; (256,4)'s 128-cap risked scratch spills.
// ---------------------------------------------------------------------------
__global__ __launch_bounds__(256, 2)
void proj_kernel(const float* __restrict__ q, const float* __restrict__ k,
                 const float* __restrict__ v,
                 const float* __restrict__ Wq, const float* __restrict__ Wk,
                 const float* __restrict__ Wv,
                 const int* __restrict__ mask,
                 const float* __restrict__ Wo,
                 unsigned short* __restrict__ qh, unsigned short* __restrict__ kh,
                 unsigned short* __restrict__ vt, unsigned short* __restrict__ wob) {
    const int z = blockIdx.z;
    if (z == 3) {   // Wo fp32 -> bf16, 1024 blocks x 256 thr x 4 elems
        int idx = (blockIdx.y * 32 + blockIdx.x) * 256 + threadIdx.x;
        f32x4 w = *(const f32x4*)(Wo + (size_t)idx * 4);
        i32x2 r = {pack2bf(w.x, w.y), pack2bf(w.z, w.w)};
        *(i32x2*)(wob + (size_t)idx * 4) = r;
        return;
    }
    const float* X = (z == 0) ? q : (z == 1) ? k : v;
    const float* W = (z == 0) ? Wq : (z == 1) ? Wk : Wv;
    unsigned short* out = (z == 0) ? qh : (z == 1) ? kh : vt;
    const float wscale = (z == 0) ? (1.44269504f * 0.03125f) : 1.0f;

    const int lane = threadIdx.x & 63;
    const int wave = threadIdx.x >> 6;
    const int l16  = lane & 15;
    const int quad = lane >> 4;
    const int bh = blockIdx.y;
    const int b = bh >> 4, h = bh & 15;
    const int n0 = blockIdx.x * 64;
    const int tok = n0 + wave * 16 + l16;

    const float* xrow = X + ((size_t)(b * N_ + tok)) * E_ + h * 64;
    bf16x8 xf[2];
    xf[0] = cvt8s(xrow + quad * 8, 1.0f);
    xf[1] = cvt8s(xrow + 32 + quad * 8, 1.0f);

    const float* Wh = W + (size_t)h * 64 * 64;
    bf16x8 wf[4][2];
#pragma unroll
    for (int t4 = 0; t4 < 4; ++t4) {
        const float* wrow = Wh + (t4 * 16 + l16) * 64;
        wf[t4][0] = cvt8s(wrow + quad * 8, wscale);
        wf[t4][1] = cvt8s(wrow + 32 + quad * 8, wscale);
    }

    const int mk = (z == 0) ? mask[b * N_ + tok] : 1;

#pragma unroll
    for (int mi = 0; mi < 4; ++mi) {
        f32x4 a = {0.f, 0.f, 0.f, 0.f};
        a = MFMA(wf[mi][0], xf[0], a);   // D: row = dout, col = token (l16)
        a = MFMA(wf[mi][1], xf[1], a);
        if (z != 2) {
            i32x2 pk = {pack2bf(a.x, a.y), pack2bf(a.z, a.w)};
            if (!mk) pk = (i32x2){0, 0};
            *(i32x2*)(out + ((size_t)bh * N_ + tok) * 64 + mi * 16 + quad * 4) = pk;
        } else {
#pragma unroll
            for (int r = 0; r < 4; ++r) {
                int dout = mi * 16 + quad * 4 + r;
                _Float16 hv = (_Float16)a[r];
                unsigned short us;
                __builtin_memcpy(&us, &hv, 2);
                out[((size_t)bh * 64 + dout) * N_ + tok] = us;
            }
        }
    }
}

// ---------------------------------------------------------------------------
// Fallback (only if workspace too small for a non-aliased wob).
__global__ __launch_bounds__(256)
void cvt_wo_kernel(const float* __restrict__ wo, unsigned short* __restrict__ wob) {
    int idx = blockIdx.x * 256 + threadIdx.x;
    f32x4 v = *(const f32x4*)(wo + (size_t)idx * 4);
    i32x2 r = {pack2bf(v.x, v.y), pack2bf(v.z, v.w)};
    *(i32x2*)(wob + (size_t)idx * 4) = r;
}

// ---------------------------------------------------------------------------
// Flash attention (round-2 proven structure, unchanged: 54.6 us).
// PV uses v_mfma_f32_16x16x16_f16 whose B-operand layout EQUALS the QK C/D
// layout -> P needs NO cross-lane transform.  V stored/staged as f16.
// K dbuf [64][72]; V triple-buffer [64][76] (2-way residue conflicts only).
// PV(t-1) pipelined behind QK(t).  No-max softmax; qh pre-scaled+masked.
// One barrier/iter.  grid (16,32)=512 (XCD swizzle: 4 heads/XCD).
// setprio(1) spans QK+PV MFMA clusters (T5, m191: +1.1us measured r2).
// ---------------------------------------------------------------------------
__global__ __launch_bounds__(256, 2)
void attn_kernel(const unsigned short* __restrict__ qh,
                 const unsigned short* __restrict__ kh,
                 const unsigned short* __restrict__ vt,
                 unsigned short* __restrict__ attnb) {
    __shared__ short Kb[2][64 * 72];   // 18 KB
    __shared__ short Vb[3][64 * 76];   // 28.5 KB

    const int tid  = threadIdx.x;
    const int lane = tid & 63;
    const int wave = tid >> 6;
    const int l16  = lane & 15;
    const int quad = lane >> 4;

    const int flat = blockIdx.y * gridDim.x + blockIdx.x;   // 0..511
    const int qblk = flat >> 5;
    const int rem  = flat & 31;
    const int bh   = ((rem & 7) << 2) | (rem >> 3);          // 4 heads per XCD
    const int b = bh >> 4, h = bh & 15;
    const int q0 = qblk * 128 + wave * 32;

    const unsigned short* kbase = kh + (size_t)bh * N_ * 64;
    const unsigned short* vbase = vt + (size_t)bh * 64 * N_;

    const int c0i = tid;
    const int c1i = tid + 256;
    const int k0o = (c0i >> 3) * 72 + (c0i & 7) * 8;
    const int k1o = (c1i >> 3) * 72 + (c1i & 7) * 8;
    const int v0o = (c0i >> 3) * 76 + (c0i & 7) * 8;
    const int v1o = (c1i >> 3) * 76 + (c1i & 7) * 8;

    short* kcur  = &Kb[0][0];
    short* knext = &Kb[1][0];
    short* vprev = &Vb[2][0];
    short* vcur  = &Vb[0][0];
    short* vnext = &Vb[1][0];

    bf16x8 qf[2][2];
#pragma unroll
    for (int qi = 0; qi < 2; ++qi) {
        const unsigned short* qrow = qh + ((size_t)bh * N_ + q0 + qi * 16 + l16) * 64;
        qf[qi][0] = *(const bf16x8*)(qrow + quad * 8);
        qf[qi][1] = *(const bf16x8*)(qrow + 32 + quad * 8);
    }

    f32x4 psum[2] = {{0.f, 0.f, 0.f, 0.f}, {0.f, 0.f, 0.f, 0.f}};
    f32x4 o[4][2];
#pragma unroll
    for (int mi = 0; mi < 4; ++mi)
#pragma unroll
        for (int qi = 0; qi < 2; ++qi) o[mi][qi] = (f32x4){0.f, 0.f, 0.f, 0.f};

    f16x4 pf[2][4];   // saved P frags (16x16x16 B-operand) from previous tile

    // stage tile 0
    bf16x8 gK0, gK1, gV0, gV1;
    gK0 = *(const bf16x8*)(kbase + c0i * 8);
    gK1 = *(const bf16x8*)(kbase + c1i * 8);
    gV0 = *(const bf16x8*)(vbase + (size_t)(c0i >> 3) * N_ + (c0i & 7) * 8);
    gV1 = *(const bf16x8*)(vbase + (size_t)(c1i >> 3) * N_ + (c1i & 7) * 8);
    *(bf16x8*)(kcur + k0o) = gK0;
    *(bf16x8*)(kcur + k1o) = gK1;
    *(bf16x8*)(vcur + v0o) = gV0;
    *(bf16x8*)(vcur + v1o) = gV1;
    __syncthreads();

    for (int kt = 0; kt < N_ / 64; ++kt) {
        // global prefetch of tile kt+1
        if (kt + 1 < N_ / 64) {
            const int k0n = (kt + 1) * 64;
            gK0 = *(const bf16x8*)(kbase + (size_t)k0n * 64 + c0i * 8);
            gK1 = *(const bf16x8*)(kbase + (size_t)k0n * 64 + c1i * 8);
            gV0 = *(const bf16x8*)(vbase + (size_t)(c0i >> 3) * N_ + k0n + (c0i & 7) * 8);
            gV1 = *(const bf16x8*)(vbase + (size_t)(c1i >> 3) * N_ + k0n + (c1i & 7) * 8);
        }

        // K frags + QK^T for tile kt  (high prio: MFMA cluster)
        __builtin_amdgcn_s_setprio(1);
        bf16x8 ka[4][2];
#pragma unroll
        for (int t4 = 0; t4 < 4; ++t4) {
            ka[t4][0] = *(const bf16x8*)(kcur + (t4 * 16 + l16) * 72 + quad * 8);
            ka[t4][1] = *(const bf16x8*)(kcur + (t4 * 16 + l16) * 72 + 32 + quad * 8);
        }
        f32x4 s[2][4];
#pragma unroll
        for (int qi = 0; qi < 2; ++qi)
#pragma unroll
            for (int t4 = 0; t4 < 4; ++t4) {
                f32x4 z = {0.f, 0.f, 0.f, 0.f};
                z = MFMA(ka[t4][0], qf[qi][0], z);
                z = MFMA(ka[t4][1], qf[qi][1], z);
                s[qi][t4] = z;
            }

        // PV for tile kt-1 (independent of this iter's chain)
        if (kt > 0) {
#pragma unroll
            for (int mi = 0; mi < 4; ++mi) {
#pragma unroll
                for (int t4 = 0; t4 < 4; ++t4) {
                    f16x4 va = *(const f16x4*)(vprev + (mi * 16 + l16) * 76 +
                                               t4 * 16 + quad * 4);
#pragma unroll
                    for (int qi = 0; qi < 2; ++qi)
                        o[mi][qi] = MFMA16(va, pf[qi][t4], o[mi][qi]);
                }
            }
        }
        __builtin_amdgcn_s_setprio(0);

        // softmax tile kt -> pf (NO transform: C-layout == 16x16x16 B-layout)
#pragma unroll
        for (int qi = 0; qi < 2; ++qi) {
#pragma unroll
            for (int t4 = 0; t4 < 4; ++t4) {
                f32x4 p;
#pragma unroll
                for (int r = 0; r < 4; ++r) p[r] = __builtin_amdgcn_exp2f(s[qi][t4][r]);
                psum[qi] += p;
                pf[qi][t4] = pack4f16(p);
            }
        }

        // stage tile kt+1, one barrier
        if (kt + 1 < N_ / 64) {
            *(bf16x8*)(knext + k0o) = gK0;
            *(bf16x8*)(knext + k1o) = gK1;
            *(bf16x8*)(vnext + v0o) = gV0;
            *(bf16x8*)(vnext + v1o) = gV1;
            __syncthreads();
        }

        // rotate buffers
        short* t = kcur; kcur = knext; knext = t;
        short* tv = vprev; vprev = vcur; vcur = vnext; vnext = tv;
    }

    // drain: PV for the last tile
    __builtin_amdgcn_s_setprio(1);
#pragma unroll
    for (int mi = 0; mi < 4; ++mi) {
#pragma unroll
        for (int t4 = 0; t4 < 4; ++t4) {
            f16x4 va = *(const f16x4*)(vprev + (mi * 16 + l16) * 76 +
                                       t4 * 16 + quad * 4);
#pragma unroll
            for (int qi = 0; qi < 2; ++qi)
                o[mi][qi] = MFMA16(va, pf[qi][t4], o[mi][qi]);
        }
    }
    __builtin_amdgcn_s_setprio(0);

    // row-sum reduction (once per kernel, not per iter)
#pragma unroll
    for (int qi = 0; qi < 2; ++qi) {
        float rs = psum[qi].x + psum[qi].y + psum[qi].z + psum[qi].w;
        rs += __shfl_xor(rs, 16);
        rs += __shfl_xor(rs, 32);
        const float inv = 1.0f / rs;
        const int qrow_idx = q0 + qi * 16 + l16;
#pragma unroll
        for (int mi = 0; mi < 4; ++mi) {
            f32x4 ov = o[mi][qi];
            i32x2 pkk = {pack2bf(ov.x * inv, ov.y * inv),
                         pack2bf(ov.z * inv, ov.w * inv)};
            int d0 = mi * 16 + quad * 4;
            *(i32x2*)(attnb + ((size_t)(b * N_ + qrow_idx)) * E_ + h * 64 + d0) = pkk;
        }
    }
}

// ---------------------------------------------------------------------------
// out = attnb(4096x1024 bf16) @ wob^T(1024x1024) -> fp32.  Round-0 inner
// (128x128 tile, BK=32, global_load_lds w16, dbuf chunk-linear LDS, 512 thr
// = 8 waves of 64x32) + NEW XCD-chunked block mapping: flat&7 = XCD owns
// 4 contiguous m-tiles x all 8 n-tiles, so the 8 blocks sharing an A
// row-slab sit on ONE XCD's L2 (old (32,8) grid spread them across XCDs
// -> ~8x A over-fetch from HBM).  B (2 MB bf16) fits each XCD L2.
// grid 256 1-D.
// ---------------------------------------------------------------------------
__global__ __launch_bounds__(512, 1)
void out_gemm_kernel(const unsigned short* __restrict__ A,
                     const unsigned short* __restrict__ Bw,
                     float* __restrict__ out) {
    __shared__ short As[2][128 * 32];   // 8 KB each
    __shared__ short Bs[2][128 * 32];

    const int tid  = threadIdx.x;
    const int lane = tid & 63;
    const int l16  = lane & 15;
    const int quad = lane >> 4;
    const int wave = tid >> 6;
    const int wm = wave & 1, wn = wave >> 1;

    const int flat = blockIdx.x;          // 0..255
    const int xcd  = flat & 7;
    const int sub  = flat >> 3;           // 0..31
    const int m0 = (xcd * 4 + (sub >> 3)) * 128;   // 32 m-tiles
    const int n0 = (sub & 7) * 128;                // 8 n-tiles

    const unsigned short* gA = A + (size_t)m0 * E_;
    const unsigned short* gB = Bw + (size_t)n0 * E_;

    f32x4 acc[4][2];
#pragma unroll
    for (int mt = 0; mt < 4; ++mt)
#pragma unroll
        for (int nt = 0; nt < 2; ++nt) acc[mt][nt] = (f32x4){0.f, 0.f, 0.f, 0.f};

    const int cc = tid >> 7, rr = tid & 127;
#define OG_STAGE(buf, k0)                                                        \
    {                                                                            \
        __builtin_amdgcn_global_load_lds(AS1(gA + (size_t)rr * E_ + (k0) + cc * 8), \
                                         AS3(&As[buf][tid * 8]), 16, 0, 0);      \
        __builtin_amdgcn_global_load_lds(AS1(gB + (size_t)rr * E_ + (k0) + cc * 8), \
                                         AS3(&Bs[buf][tid * 8]), 16, 0, 0);      \
    }

    OG_STAGE(0, 0)
    __syncthreads();

    for (int kt = 0; kt < E_ / 32; ++kt) {
        const int cur = kt & 1;
        if (kt + 1 < E_ / 32) OG_STAGE(cur ^ 1, (kt + 1) * 32)

        bf16x8 af[4], bf[2];
#pragma unroll
        for (int mt = 0; mt < 4; ++mt)
            af[mt] = *(const bf16x8*)(&As[cur][(quad * 128 + wm * 64 + mt * 16 + l16) * 8]);
#pragma unroll
        for (int nt = 0; nt < 2; ++nt)
            bf[nt] = *(const bf16x8*)(&Bs[cur][(quad * 128 + wn * 32 + nt * 16 + l16) * 8]);

        __builtin_amdgcn_s_setprio(1);
#pragma unroll
        for (int mt = 0; mt < 4; ++mt)
#pragma unroll
            for (int nt = 0; nt < 2; ++nt)
                acc[mt][nt] = MFMA(af[mt], bf[nt], acc[mt][nt]);
        __builtin_amdgcn_s_setprio(0);

        __syncthreads();
    }

#pragma unroll
    for (int mt = 0; mt < 4; ++mt)
#pragma unroll
        for (int nt = 0; nt < 2; ++nt)
#pragma unroll
            for (int r = 0; r < 4; ++r)
                out[(size_t)(m0 + wm * 64 + mt * 16 + quad * 4 + r) * E_ +
                    n0 + wn * 32 + nt * 16 + l16] = acc[mt][nt][r];
#undef OG_STAGE
}

// ---------------------------------------------------------------------------
extern "C" void kernel_launch(void* const* d_in, const int* in_sizes, int n_in,
                              void* d_out, int out_size, void* d_ws, size_t ws_size,
                              hipStream_t stream) {
    const float* q    = (const float*)d_in[0];
    const float* k    = (const float*)d_in[1];
    const float* v    = (const float*)d_in[2];
    const int*   mask = (const int*)d_in[3];
    const float* Wq   = (const float*)d_in[4];
    const float* Wk   = (const float*)d_in[5];
    const float* Wv   = (const float*)d_in[6];
    const float* Wo   = (const float*)d_in[7];
    float* out = (float*)d_out;

    char* ws = (char*)d_ws;
    unsigned short* qh    = (unsigned short*)(ws);
    unsigned short* kh    = (unsigned short*)(ws + (size_t)8 * 1024 * 1024);
    unsigned short* vt    = (unsigned short*)(ws + (size_t)16 * 1024 * 1024);
    unsigned short* attnb = (unsigned short*)(ws + (size_t)24 * 1024 * 1024);

    // wob: non-aliased slot at 32 MiB if the workspace allows (enables the
    // fused z==3 conversion inside proj); otherwise alias qh and convert
    // after attn (qh dead by then) with the fallback kernel.
    const bool fused_wo = ws_size >= (size_t)34 * 1024 * 1024;
    unsigned short* wob = fused_wo ? (unsigned short*)(ws + (size_t)32 * 1024 * 1024)
                                   : (unsigned short*)(ws);

    dim3 blk(256);
    proj_kernel<<<dim3(N_ / 64, BH_, fused_wo ? 4 : 3), blk, 0, stream>>>(
        q, k, v, Wq, Wk, Wv, mask, Wo, qh, kh, vt, wob);
    attn_kernel<<<dim3(16, 32), blk, 0, stream>>>(qh, kh, vt, attnb);
    if (!fused_wo)
        cvt_wo_kernel<<<dim3(E_ * E_ / 1024), blk, 0, stream>>>(Wo, wob);
    out_gemm_kernel<<<dim3(256), dim3(512), 0, stream>>>(attnb, wob, out);
}